// Round 1
// baseline (15086.169 us; speedup 1.0000x reference)
//
#include <hip/hip_runtime.h>
#include <math.h>

#define STEPS 20000
#define NS    2048
#define NBINS 200000

// ---- CDF constants for state-1 row, computed exactly as numpy does ----
// ROW_SUMS[1] = 5e7 + 0 + 3e6 + 2e4 + 7e7 = 123020000 (exact in double)
// p_i = rate_i / S (double), cumsum left-to-right (double), cast to float.
constexpr double S1d = 5e7 + 3e6 + 2e4 + 7e7;      // 123020000, exact
constexpr double P0d = 5e7 / S1d;
constexpr double P2d = 3e6 / S1d;
constexpr double P3d = 2e4 / S1d;
constexpr double P4d = 7e7 / S1d;
constexpr float C0 = (float)(P0d);                  // cdf[0] == cdf[1]
constexpr float C2 = (float)(P0d + P2d);            // cdf[2]
constexpr float C3 = (float)((P0d + P2d) + P3d);    // cdf[3]
constexpr float C4 = (float)(((P0d + P2d) + P3d) + P4d); // cdf[4] (≈1.0)

// Row rates cast to float32 (all exactly representable except 0.2 which
// rounds the same way numpy rounds it). dwell uses reciprocal multiply —
// only cum_time/hist depend on it (2% tolerance), photons do not.
constexpr float INV_R0 = 1.0f / 1e6f;
constexpr float INV_R1 = 1.0f / 123020000.0f;
constexpr float INV_R2 = 1.0f / 1e5f;
constexpr float INV_R3 = 1.0f / 0.2f;

__global__ void zero_hist_kernel(float* __restrict__ hist) {
    int i = blockIdx.x * blockDim.x + threadIdx.x;
    if (i <= NBINS) hist[i] = 0.0f;
}

// searchsorted(bins, v, side='left') with bins[i] = float(i) * 0.002f.
// Start from a safe lower bound and walk up (<= ~3 iterations: the guess is
// within 2 of the answer because 500.0f over-estimates 1/0.002f by <3e-5 rel).
__device__ __forceinline__ int bucketize(float v) {
    int lo = (int)(v * 500.0f) - 2;
    lo = lo < 0 ? 0 : lo;
    while (lo < NBINS && (float)lo * 0.002f < v) ++lo;
    return lo;
}

#define PF 16   // pipeline depth (steps per chunk); 2 chunks in flight

struct SimState {
    int   state;
    float cum;
    float zero_cnt;   // count of v==0 entries (non-photon or ind==0)
    int   cur_v;      // current photon bin (run-length aggregation)
    float cur_cnt;
};

__device__ __forceinline__ void process_chunk(
    const float* __restrict__ uc, const float* __restrict__ ue,
    int ch, float* __restrict__ pph, float* __restrict__ pcm,
    float* __restrict__ hist, SimState& st)
{
    int state = st.state;
    float cum = st.cum;
#pragma unroll
    for (int j = 0; j < PF; ++j) {
        const int s = ch * PF + j;
        const float u1 = uc[j];
        const float base = -log1pf(-ue[j]);
        // target-if-in-state-1, with t==4 and argmax-fallback both -> 0.
        // Depends only on u1 (off the sequential critical chain).
        int t1p;
        if (u1 < C2) t1p = (u1 < C0) ? 0 : 2;
        else         t1p = (u1 < C3) ? 3 : 0;
        const bool ph = (state == 0);                 // photon iff t==1 iff state==0
        const float inv = (state == 0) ? INV_R0
                        : (state == 1) ? INV_R1
                        : (state == 2) ? INV_R2 : INV_R3;
        cum += base * inv;
        pph[(size_t)s * NS] = ph ? 1.0f : 0.0f;
        pcm[(size_t)s * NS] = cum;
        state = (state == 0) ? 1 : ((state == 1) ? t1p : 0);
        // histogram with run-length aggregation
        int v = 0;
        if (ph) v = bucketize(cum);
        if (v == 0) {
            st.zero_cnt += 1.0f;
        } else if (v == st.cur_v) {
            st.cur_cnt += 1.0f;
        } else {
            if (st.cur_v > 0) atomicAdd(hist + st.cur_v, st.cur_cnt);
            st.cur_v = v;
            st.cur_cnt = 1.0f;
        }
    }
    st.state = state;
    st.cum = cum;
}

__global__ void __launch_bounds__(64)
sim_kernel(const float* __restrict__ u_cat, const float* __restrict__ u_exp,
           float* __restrict__ photons, float* __restrict__ cumt,
           float* __restrict__ hist)
{
    const int c = blockIdx.x * 64 + threadIdx.x;   // column / emitter id
    const float* pc = u_cat + c;
    const float* pe = u_exp + c;
    float* pph = photons + c;
    float* pcm = cumt + c;

    float ucA[PF], ueA[PF], ucB[PF], ueB[PF];

    // preload chunk 0 into A
#pragma unroll
    for (int j = 0; j < PF; ++j) {
        ucA[j] = pc[(size_t)j * NS];
        ueA[j] = pe[(size_t)j * NS];
    }

    SimState st;
    st.state = 0;
    st.cum = 0.0f;
    st.zero_cnt = 0.0f;
    st.cur_v = -1;
    st.cur_cnt = 0.0f;

    constexpr int NCHUNK = STEPS / PF;   // 1250, even
    for (int ch = 0; ch < NCHUNK; ch += 2) {
        // prefetch chunk ch+1 into B (always in range: ch+1 <= NCHUNK-1)
        {
            const size_t row = (size_t)(ch + 1) * PF;
#pragma unroll
            for (int j = 0; j < PF; ++j) {
                ucB[j] = pc[(row + j) * NS];
                ueB[j] = pe[(row + j) * NS];
            }
        }
        process_chunk(ucA, ueA, ch, pph, pcm, hist, st);
        // prefetch chunk ch+2 into A
        if (ch + 2 < NCHUNK) {
            const size_t row = (size_t)(ch + 2) * PF;
#pragma unroll
            for (int j = 0; j < PF; ++j) {
                ucA[j] = pc[(row + j) * NS];
                ueA[j] = pe[(row + j) * NS];
            }
        }
        process_chunk(ucB, ueB, ch + 1, pph, pcm, hist, st);
    }

    // flush histogram accumulators
    if (st.zero_cnt > 0.0f) atomicAdd(hist + 0, st.zero_cnt);
    if (st.cur_v > 0) atomicAdd(hist + st.cur_v, st.cur_cnt);
}

extern "C" void kernel_launch(void* const* d_in, const int* in_sizes, int n_in,
                              void* d_out, int out_size, void* d_ws, size_t ws_size,
                              hipStream_t stream) {
    const float* u_cat = (const float*)d_in[0];
    const float* u_exp = (const float*)d_in[1];
    float* out = (float*)d_out;
    float* photons = out;                                  // (STEPS, NS)
    float* cumt    = out + (size_t)STEPS * NS;             // (STEPS, NS)
    float* hist    = out + 2 * (size_t)STEPS * NS;         // (NBINS+1,)

    zero_hist_kernel<<<(NBINS + 1 + 255) / 256, 256, 0, stream>>>(hist);
    sim_kernel<<<NS / 64, 64, 0, stream>>>(u_cat, u_exp, photons, cumt, hist);
}

// Round 2
// 3873.689 us; speedup vs baseline: 3.8945x; 3.8945x over previous
//
#include <hip/hip_runtime.h>
#include <math.h>

#define STEPS  20000
#define NS     2048
#define NBINS  200000
#define SEGLEN 80                 // steps per segment (multiple of 16)
#define NSEG   (STEPS / SEGLEN)   // 250
#define NT     (NSEG * NS)        // 512000 segment-threads
#define WPS    (SEGLEN / 16)      // 5 packed t1p words per segment

// ---- CDF constants for state-1 row, computed exactly as numpy does ----
constexpr double S1d = 5e7 + 3e6 + 2e4 + 7e7;      // 123020000, exact
constexpr double P0d = 5e7 / S1d;
constexpr double P2d = 3e6 / S1d;
constexpr double P3d = 2e4 / S1d;
constexpr float C0 = (float)(P0d);                  // cdf[0] == cdf[1]
constexpr float C2 = (float)(P0d + P2d);            // cdf[2]
constexpr float C3 = (float)((P0d + P2d) + P3d);    // cdf[3]

constexpr float INV_R0 = 1.0f / 1e6f;
constexpr float INV_R1 = 1.0f / 123020000.0f;
constexpr float INV_R2 = 1.0f / 1e5f;
constexpr float INV_R3 = 1.0f / 0.2f;               // == 5.0f

// ---- workspace layout (bytes) ----
#define WS_T1P    0                     // uint32 [WPS][NT]   10,240,000 B
#define WS_MAPS   10240000              // uint8  [NT]           512,000 B
#define WS_ENTER  10752000              // uint8  [NT]           512,000 B
#define WS_SUMS   11264000              // float  [NT]         2,048,000 B
#define WS_OFFS   13312000              // float  [NT]         2,048,000 B
#define WS_PCNT   15360000              // int                          4 B

__global__ void zero_kernel(float* __restrict__ hist, int* __restrict__ pcount) {
    int i = blockIdx.x * blockDim.x + threadIdx.x;
    if (i <= NBINS) hist[i] = 0.0f;
    if (i == 0) *pcount = 0;
}

// searchsorted(bins, v, 'left') with bins[i] = float(i)*0.002f (bit-identical).
__device__ __forceinline__ int bucketize(float v) {
    int lo = (int)(v * 500.0f) - 2;
    lo = lo < 0 ? 0 : lo;
    while (lo < NBINS && (float)lo * 0.002f < v) ++lo;
    return lo;
}

// K1: per-segment transition-map composition + packed t1p cache.
__global__ void __launch_bounds__(256)
map_kernel(const float* __restrict__ u_cat,
           unsigned int* __restrict__ t1p, unsigned char* __restrict__ maps) {
    const int t = blockIdx.x * 256 + threadIdx.x;
    const int col = t & (NS - 1), seg = t >> 11;
    const float* pc = u_cat + (size_t)seg * SEGLEN * NS + col;
    int c0 = 0, c1 = 1, c2 = 2, c3 = 3;   // identity map
#pragma unroll
    for (int k = 0; k < WPS; ++k) {
        unsigned int w = 0;
#pragma unroll
        for (int j = 0; j < 16; ++j) {
            const float u1 = pc[(size_t)(k * 16 + j) * NS];
            int te;
            if (u1 < C2) te = (u1 < C0) ? 0 : 2;
            else         te = (u1 < C3) ? 3 : 0;
            w |= (unsigned int)te << (2 * j);
            c0 = (c0 == 0) ? 1 : ((c0 == 1) ? te : 0);
            c1 = (c1 == 0) ? 1 : ((c1 == 1) ? te : 0);
            c2 = (c2 == 0) ? 1 : ((c2 == 1) ? te : 0);
            c3 = (c3 == 0) ? 1 : ((c3 == 1) ? te : 0);
        }
        t1p[k * NT + t] = w;
    }
    maps[t] = (unsigned char)(c0 | (c1 << 2) | (c2 << 4) | (c3 << 6));
}

// K2: per-column scan of segment maps -> entering state per segment (exact).
__global__ void scan_state_kernel(const unsigned char* __restrict__ maps,
                                  unsigned char* __restrict__ enter) {
    const int col = blockIdx.x * blockDim.x + threadIdx.x;  // 0..2047
    int state = 0;
    for (int g = 0; g < NSEG; ++g) {
        enter[g * NS + col] = (unsigned char)state;
        const unsigned char m = maps[g * NS + col];
        state = (m >> (2 * state)) & 3;
    }
}

// K3: per-segment dwell sums.
__global__ void __launch_bounds__(256)
dwell_kernel(const float* __restrict__ u_exp, const unsigned int* __restrict__ t1p,
             const unsigned char* __restrict__ enter, float* __restrict__ sums) {
    const int t = blockIdx.x * 256 + threadIdx.x;
    const int col = t & (NS - 1), seg = t >> 11;
    const float* pe = u_exp + (size_t)seg * SEGLEN * NS + col;
    int state = enter[t];
    float sum = 0.0f;
#pragma unroll
    for (int k = 0; k < WPS; ++k) {
        const unsigned int w = t1p[k * NT + t];
#pragma unroll
        for (int j = 0; j < 16; ++j) {
            const float ue = pe[(size_t)(k * 16 + j) * NS];
            const float base = -log1pf(-ue);
            const float inv = (state == 0) ? INV_R0
                            : (state == 1) ? INV_R1
                            : (state == 2) ? INV_R2 : INV_R3;
            sum += base * inv;
            const int te = (w >> (2 * j)) & 3;
            state = (state == 0) ? 1 : ((state == 1) ? te : 0);
        }
    }
    sums[t] = sum;
}

// K4: per-column exclusive scan of segment sums -> time offsets.
__global__ void scan_time_kernel(const float* __restrict__ sums,
                                 float* __restrict__ offs) {
    const int col = blockIdx.x * blockDim.x + threadIdx.x;  // 0..2047
    float off = 0.0f;
    for (int g = 0; g < NSEG; ++g) {
        offs[g * NS + col] = off;
        off += sums[g * NS + col];
    }
}

// K5: final replay — photons, cum_time, histogram.
__global__ void __launch_bounds__(256)
final_kernel(const float* __restrict__ u_exp, const unsigned int* __restrict__ t1p,
             const unsigned char* __restrict__ enter, const float* __restrict__ offs,
             float* __restrict__ photons, float* __restrict__ cumt,
             float* __restrict__ hist, int* __restrict__ pcount) {
    const int t = blockIdx.x * 256 + threadIdx.x;
    const int col = t & (NS - 1), seg = t >> 11;
    const size_t base_s = (size_t)seg * SEGLEN;
    const float* pe = u_exp + base_s * NS + col;
    float* pph = photons + base_s * NS + col;
    float* pcm = cumt + base_s * NS + col;

    int state = enter[t];
    float cum = offs[t];
    int my_photons = 0;
    int cur_v = -1;
    float cur_cnt = 0.0f;
#pragma unroll
    for (int k = 0; k < WPS; ++k) {
        const unsigned int w = t1p[k * NT + t];
#pragma unroll
        for (int j = 0; j < 16; ++j) {
            const size_t row = (size_t)(k * 16 + j) * NS;
            const float ue = pe[row];
            const float dwell_base = -log1pf(-ue);
            const float inv = (state == 0) ? INV_R0
                            : (state == 1) ? INV_R1
                            : (state == 2) ? INV_R2 : INV_R3;
            cum += dwell_base * inv;
            const bool ph = (state == 0);
            pph[row] = ph ? 1.0f : 0.0f;
            pcm[row] = cum;
            if (ph) {
                ++my_photons;
                const int v = bucketize(cum);
                if (v == cur_v) {
                    cur_cnt += 1.0f;
                } else {
                    if (cur_v > 0) atomicAdd(hist + cur_v, cur_cnt);
                    cur_v = v;
                    cur_cnt = 1.0f;
                }
            }
            const int te = (w >> (2 * j)) & 3;
            state = (state == 0) ? 1 : ((state == 1) ? te : 0);
        }
    }
    if (cur_v > 0) atomicAdd(hist + cur_v, cur_cnt);
    // wave-reduce photon count, one atomic per wave
#pragma unroll
    for (int off = 32; off >= 1; off >>= 1)
        my_photons += __shfl_down(my_photons, off, 64);
    if ((threadIdx.x & 63) == 0) atomicAdd(pcount, my_photons);
}

// K6: hist[0] = total entries - total photons (exact integer arithmetic).
__global__ void hist0_kernel(float* __restrict__ hist, const int* __restrict__ pcount) {
    if (threadIdx.x == 0 && blockIdx.x == 0)
        hist[0] = (float)((double)STEPS * NS - (double)(*pcount));
}

extern "C" void kernel_launch(void* const* d_in, const int* in_sizes, int n_in,
                              void* d_out, int out_size, void* d_ws, size_t ws_size,
                              hipStream_t stream) {
    const float* u_cat = (const float*)d_in[0];
    const float* u_exp = (const float*)d_in[1];
    float* out = (float*)d_out;
    float* photons = out;                                  // (STEPS, NS)
    float* cumt    = out + (size_t)STEPS * NS;             // (STEPS, NS)
    float* hist    = out + 2 * (size_t)STEPS * NS;         // (NBINS+1,)

    char* ws = (char*)d_ws;
    unsigned int*  t1p   = (unsigned int*)(ws + WS_T1P);
    unsigned char* maps  = (unsigned char*)(ws + WS_MAPS);
    unsigned char* enter = (unsigned char*)(ws + WS_ENTER);
    float*         sums  = (float*)(ws + WS_SUMS);
    float*         offs  = (float*)(ws + WS_OFFS);
    int*           pcnt  = (int*)(ws + WS_PCNT);

    zero_kernel<<<(NBINS + 1 + 255) / 256, 256, 0, stream>>>(hist, pcnt);
    map_kernel<<<NT / 256, 256, 0, stream>>>(u_cat, t1p, maps);
    scan_state_kernel<<<NS / 256, 256, 0, stream>>>(maps, enter);
    dwell_kernel<<<NT / 256, 256, 0, stream>>>(u_exp, t1p, enter, sums);
    scan_time_kernel<<<NS / 256, 256, 0, stream>>>(sums, offs);
    final_kernel<<<NT / 256, 256, 0, stream>>>(u_exp, t1p, enter, offs,
                                               photons, cumt, hist, pcnt);
    hist0_kernel<<<1, 64, 0, stream>>>(hist, pcnt);
}

// Round 3
// 920.810 us; speedup vs baseline: 16.3836x; 4.2068x over previous
//
#include <hip/hip_runtime.h>
#include <math.h>

#define STEPS  20000
#define NS     2048
#define NBINS  200000
#define SEGLEN 80                 // steps per segment
#define NSEG   250                // STEPS/SEGLEN
#define NT     512000             // NSEG*NS segment-threads
#define WPS    5                  // 16-step words per segment

// ---- CDF constants for state-1 row, computed exactly as numpy does ----
constexpr double S1d = 5e7 + 3e6 + 2e4 + 7e7;      // 123020000, exact
constexpr double P0d = 5e7 / S1d;
constexpr double P2d = 3e6 / S1d;
constexpr double P3d = 2e4 / S1d;
constexpr float C0 = (float)(P0d);                  // cdf[0] == cdf[1]
constexpr float C2 = (float)(P0d + P2d);            // cdf[2]
constexpr float C3 = (float)((P0d + P2d) + P3d);    // cdf[3]

constexpr float INV_R0 = 1.0f / 1e6f;
constexpr float INV_R1 = 1.0f / 123020000.0f;
constexpr float INV_R2 = 1.0f / 1e5f;
constexpr float INV_R3 = 5.0f;                      // 1/0.2

// ---- workspace layout (bytes); total 23,552,004 ----
#define WS_T1P   0u          // u32 [WPS][NT]  10,240,000
#define WS_MAPS  10240000u   // u8  [NT]          512,000
#define WS_PCNT4 10752000u   // u32 [NT]        2,048,000
#define WS_SUMS4 12800000u   // f4  [NT]        8,192,000
#define WS_ENTER 20992000u   // u8  [NT]          512,000
#define WS_OFFS  21504000u   // f32 [NT]        2,048,000
#define WS_PTOT  23552000u   // int

__device__ __forceinline__ int te_decode(float u1) {
    return (u1 < C2) ? ((u1 < C0) ? 0 : 2) : ((u1 < C3) ? 3 : 0);
}
__device__ __forceinline__ int next_state(int s, int te) {
    return (s == 0) ? 1 : ((s == 1) ? te : 0);
}
__device__ __forceinline__ float inv_of(int s) {
    return (s == 0) ? INV_R0 : ((s == 1) ? INV_R1 : ((s == 2) ? INV_R2 : INV_R3));
}
__device__ __forceinline__ float dwell_base(float ue) {
    return -__logf(1.0f - ue);      // == -log1p(-ue), cheap (v_log_f32)
}

// searchsorted(bins, v, 'left'), bins[i]=float(i)*0.002f. Branchless: guess
// is within +-2 of truth, walk-up fixed 4 steps, clamp to NBINS.
__device__ __forceinline__ int bucketize(float v) {
    int lo = (int)(v * 500.0f) - 2;
    lo = lo < 0 ? 0 : lo;
#pragma unroll
    for (int i = 0; i < 4; ++i) lo += ((float)lo * 0.002f < v) ? 1 : 0;
    return lo > NBINS ? NBINS : lo;
}

__global__ void zero_kernel(float* __restrict__ hist, int* __restrict__ ptot) {
    int i = blockIdx.x * blockDim.x + threadIdx.x;
    if (i <= NBINS) hist[i] = 0.0f;
    if (i == 0) *ptot = 0;
}

// K1: per-segment transition maps, packed te stream, photon counts and dwell
// sums for all 4 possible entering states (one pass over u_cat + u_exp).
__global__ void __launch_bounds__(256)
map_dwell_kernel(const float* __restrict__ u_cat, const float* __restrict__ u_exp,
                 unsigned int* __restrict__ t1p, unsigned char* __restrict__ maps,
                 unsigned int* __restrict__ pcnt4, float4* __restrict__ sums4)
{
    const int t = blockIdx.x * 256 + threadIdx.x;
    const size_t base = (size_t)(t >> 11) * SEGLEN * NS + (t & (NS - 1));

    float uc[2][8], ue[2][8];
#pragma unroll
    for (int j = 0; j < 8; ++j) {
        uc[0][j] = __builtin_nontemporal_load(u_cat + base + (size_t)j * NS);
        ue[0][j] = u_exp[base + (size_t)j * NS];
    }
    int c0 = 0, c1 = 1, c2 = 2, c3 = 3;
    int n0 = 0, n1 = 0, n2 = 0, n3 = 0;
    float s0 = 0.f, s1 = 0.f, s2 = 0.f, s3 = 0.f;
    unsigned int wcur = 0;
#pragma unroll
    for (int ch = 0; ch < 10; ++ch) {
        const int cur = ch & 1, nxt = cur ^ 1;
        if (ch < 9) {
            const size_t rb = base + (size_t)(ch + 1) * 8 * NS;
#pragma unroll
            for (int j = 0; j < 8; ++j) {
                uc[nxt][j] = __builtin_nontemporal_load(u_cat + rb + (size_t)j * NS);
                ue[nxt][j] = u_exp[rb + (size_t)j * NS];
            }
        }
#pragma unroll
        for (int j = 0; j < 8; ++j) {
            const int s = ch * 8 + j;
            const int te = te_decode(uc[cur][j]);
            wcur |= (unsigned int)te << (2 * (s & 15));
            const float b = dwell_base(ue[cur][j]);
            n0 += (c0 == 0); n1 += (c1 == 0); n2 += (c2 == 0); n3 += (c3 == 0);
            s0 += b * inv_of(c0); s1 += b * inv_of(c1);
            s2 += b * inv_of(c2); s3 += b * inv_of(c3);
            c0 = next_state(c0, te); c1 = next_state(c1, te);
            c2 = next_state(c2, te); c3 = next_state(c3, te);
        }
        if (cur == 1) { t1p[(ch >> 1) * NT + t] = wcur; wcur = 0; }
    }
    maps[t]  = (unsigned char)(c0 | (c1 << 2) | (c2 << 4) | (c3 << 6));
    pcnt4[t] = (unsigned int)(n0 | (n1 << 8) | (n2 << 16) | (n3 << 24));
    sums4[t] = make_float4(s0, s1, s2, s3);
}

// K2: per-column scan over 250 segments: entering state, entering time,
// and exact total photon count (block-reduced, 8 atomics total).
__global__ void __launch_bounds__(256)
scan_kernel(const unsigned char* __restrict__ maps, const unsigned int* __restrict__ pcnt4,
            const float4* __restrict__ sums4, unsigned char* __restrict__ enter,
            float* __restrict__ offs, int* __restrict__ ptot)
{
    const int col = blockIdx.x * 256 + threadIdx.x;   // 0..2047
    int state = 0, P = 0;
    float off = 0.0f;

    unsigned char mpA[5], mpB[5];
    unsigned int  mtA[5], mtB[5];
    float4        s4A[5], s4B[5];
#pragma unroll
    for (int j = 0; j < 5; ++j) {
        const int idx = j * NS + col;
        mpA[j] = maps[idx]; mtA[j] = pcnt4[idx]; s4A[j] = sums4[idx];
    }
#define SCAN_PREFETCH(BUFm, BUFt, BUFs, B)                                   \
    {   const int gb = (B) * 5;                                              \
        _Pragma("unroll")                                                    \
        for (int j = 0; j < 5; ++j) {                                        \
            const int idx = (gb + j) * NS + col;                             \
            BUFm[j] = maps[idx]; BUFt[j] = pcnt4[idx]; BUFs[j] = sums4[idx]; \
        } }
#define SCAN_PROCESS(BUFm, BUFt, BUFs, B)                                    \
    {   const int gb = (B) * 5;                                              \
        _Pragma("unroll")                                                    \
        for (int j = 0; j < 5; ++j) {                                        \
            const int idx = (gb + j) * NS + col;                             \
            enter[idx] = (unsigned char)state;                               \
            offs[idx]  = off;                                                \
            const float4 s = BUFs[j];                                        \
            const float lo = (state & 1) ? s.y : s.x;                        \
            const float hi = (state & 1) ? s.w : s.z;                        \
            off += (state & 2) ? hi : lo;                                    \
            P += (int)((BUFt[j] >> (8 * state)) & 0xffu);                    \
            state = (int)((BUFm[j] >> (2 * state)) & 3u);                    \
        } }
    for (int b = 0; b < 50; b += 2) {
        SCAN_PREFETCH(mpB, mtB, s4B, b + 1)
        SCAN_PROCESS(mpA, mtA, s4A, b)
        if (b + 2 < 50) SCAN_PREFETCH(mpA, mtA, s4A, b + 2)
        SCAN_PROCESS(mpB, mtB, s4B, b + 1)
    }
#undef SCAN_PREFETCH
#undef SCAN_PROCESS

    __shared__ int red[256];
    red[threadIdx.x] = P;
    __syncthreads();
#pragma unroll
    for (int s = 128; s > 0; s >>= 1) {
        if (threadIdx.x < s) red[threadIdx.x] += red[threadIdx.x + s];
        __syncthreads();
    }
    if (threadIdx.x == 0) atomicAdd(ptot, red[0]);
}

// hist[0] = total entries - total photons (exact).
__global__ void hist0_kernel(float* __restrict__ hist, const int* __restrict__ ptot) {
    if (threadIdx.x == 0 && blockIdx.x == 0)
        hist[0] = (float)(40960000 - *ptot);
}

// Wave-aggregated histogram flush: one atomic per distinct bin per wave.
// Must be called with all 64 lanes converged.
__device__ __forceinline__ void wave_flush(float* __restrict__ hist, int v, float cnt) {
    unsigned long long active = __ballot(v > 0);
    while (active) {
        const int leader = __ffsll((long long)active) - 1;
        const int vl = __shfl(v, leader, 64);
        const unsigned long long match = __ballot(v == vl);
        float c = (v == vl) ? cnt : 0.0f;
#pragma unroll
        for (int o = 32; o > 0; o >>= 1) c += __shfl_xor(c, o, 64);
        if ((int)(threadIdx.x & 63) == leader) atomicAdd(hist + vl, c);
        active &= ~match;
    }
}

// K3: final replay — photons, cum_time, histogram.
__global__ void __launch_bounds__(256)
final_kernel(const float* __restrict__ u_exp, const unsigned int* __restrict__ t1p,
             const unsigned char* __restrict__ enter, const float* __restrict__ offs,
             float* __restrict__ photons, float* __restrict__ cumt,
             float* __restrict__ hist)
{
    const int t = blockIdx.x * 256 + threadIdx.x;
    const size_t base = (size_t)(t >> 11) * SEGLEN * NS + (t & (NS - 1));
    const float* pe = u_exp + base;
    float* pph = photons + base;
    float* pcm = cumt + base;

    unsigned int w[WPS];
#pragma unroll
    for (int k = 0; k < WPS; ++k) w[k] = t1p[k * NT + t];

    float ue[2][16];
#pragma unroll
    for (int j = 0; j < 16; ++j) ue[0][j] = pe[(size_t)j * NS];

    int state = enter[t];
    float cum = offs[t];
    int v0 = 0, v1 = 0;           // up to two register run slots (bins ascend)
    float r0 = 0.0f, r1 = 0.0f;

#pragma unroll
    for (int ch = 0; ch < 5; ++ch) {
        const int cur = ch & 1, nxt = cur ^ 1;
        if (ch < 4) {
            const size_t rb = (size_t)(ch + 1) * 16 * NS;
#pragma unroll
            for (int j = 0; j < 16; ++j) ue[nxt][j] = pe[rb + (size_t)j * NS];
        }
#pragma unroll
        for (int j = 0; j < 16; ++j) {
            const size_t row = (size_t)(ch * 16 + j) * NS;
            cum += dwell_base(ue[cur][j]) * inv_of(state);
            const bool ph = (state == 0);
            __builtin_nontemporal_store(ph ? 1.0f : 0.0f, pph + row);
            __builtin_nontemporal_store(cum, pcm + row);
            if (ph) {
                const int v = bucketize(cum);
                if (v == v0)       r0 += 1.0f;
                else if (v == v1)  r1 += 1.0f;
                else if (v0 == 0) { v0 = v; r0 = 1.0f; }
                else if (v1 == 0) { v1 = v; r1 = 1.0f; }
                else atomicAdd(hist + v, 1.0f);          // 3rd distinct bin: rare
            }
            state = next_state(state, (int)((w[ch] >> (2 * j)) & 3u));
        }
    }
    wave_flush(hist, v0, r0);
    wave_flush(hist, v1, r1);
}

extern "C" void kernel_launch(void* const* d_in, const int* in_sizes, int n_in,
                              void* d_out, int out_size, void* d_ws, size_t ws_size,
                              hipStream_t stream) {
    const float* u_cat = (const float*)d_in[0];
    const float* u_exp = (const float*)d_in[1];
    float* out = (float*)d_out;
    float* photons = out;                                  // (STEPS, NS)
    float* cumt    = out + (size_t)STEPS * NS;             // (STEPS, NS)
    float* hist    = out + 2 * (size_t)STEPS * NS;         // (NBINS+1,)

    char* ws = (char*)d_ws;
    unsigned int*  t1p   = (unsigned int*)(ws + WS_T1P);
    unsigned char* maps  = (unsigned char*)(ws + WS_MAPS);
    unsigned int*  pcnt4 = (unsigned int*)(ws + WS_PCNT4);
    float4*        sums4 = (float4*)(ws + WS_SUMS4);
    unsigned char* enter = (unsigned char*)(ws + WS_ENTER);
    float*         offs  = (float*)(ws + WS_OFFS);
    int*           ptot  = (int*)(ws + WS_PTOT);

    zero_kernel<<<(NBINS + 1 + 255) / 256, 256, 0, stream>>>(hist, ptot);
    map_dwell_kernel<<<NT / 256, 256, 0, stream>>>(u_cat, u_exp, t1p, maps, pcnt4, sums4);
    scan_kernel<<<NS / 256, 256, 0, stream>>>(maps, pcnt4, sums4, enter, offs, ptot);
    hist0_kernel<<<1, 64, 0, stream>>>(hist, ptot);
    final_kernel<<<NT / 256, 256, 0, stream>>>(u_exp, t1p, enter, offs, photons, cumt, hist);
}